// Round 1
// baseline (1171.188 us; speedup 1.0000x reference)
//
#include <hip/hip_runtime.h>
#include <math.h>

#define N_ATOMS 50000
#define P_PAIRS 1600000
#define TA 16

__device__ __forceinline__ float gelu_exact(float x) {
    return 0.5f * x * (1.0f + erff(x * 0.70710678118654752440f));
}

// One thread per (pair, component): c in [0,16) -> gs, c in [16,64) -> gv (d*16+g)
__global__ __launch_bounds__(256) void scatter_kernel(
    const int* __restrict__ idx_j,
    const float* __restrict__ gs,
    const float* __restrict__ gv,
    float* __restrict__ acc)
{
    int t = blockIdx.x * 256 + threadIdx.x;   // up to 102.4M < 2^31
    int p = t >> 6;
    int c = t & 63;
    int idx = idx_j[p];
    float v = (c < 16) ? gs[p * 16 + c] : gv[p * 48 + (c - 16)];
    atomicAdd(acc + idx * 64 + c, v);
}

__global__ __launch_bounds__(256, 2) void fused_atom_kernel(
    const float* __restrict__ emb,
    const float* __restrict__ qch,
    const float* __restrict__ acc,
    const float* __restrict__ agh,   // (128,16,32) -> [a*512 + g*32 + h]
    const float* __restrict__ W_gf,  // (16,128)
    const float* __restrict__ W1, const float* __restrict__ b1,   // (320,256)
    const float* __restrict__ W2, const float* __restrict__ b2,   // (256,128)
    const float* __restrict__ W3, const float* __restrict__ b3,   // (128,130)
    float* __restrict__ out)
{
    // bufA: embT [128][16]  then  h1T [256][16]
    // bufB: U    [16][512]  then  h2T [128][16]
    __shared__ __align__(16) float s_bufA[16 * 256];
    __shared__ __align__(16) float s_bufB[16 * 512];
    __shared__ __align__(16) float s_msgT[320 * 16];   // [k][atom]
    __shared__ __align__(16) float s_gs[16 * 16];      // [atom][g]
    __shared__ __align__(16) float s_gv[16 * 48];      // [atom][d*16+g]
    __shared__ __align__(16) float s_q[16];

    const int tid = threadIdx.x;
    const int n0 = blockIdx.x * TA;

    float* s_embT = s_bufA;   // [a][atom]
    float* s_U    = s_bufB;   // [atom][gh]
    float* s_h1T  = s_bufA;   // [k][atom]
    float* s_h2T  = s_bufB;   // [k][atom]

    // ---- stage emb (transposed into LDS), per-atom gs/gv sums, q ----
    #pragma unroll
    for (int i = 0; i < 2; i++) {
        int ii = tid + i * 256;           // float4 index, 512 total
        int atom = ii >> 5;               // 32 float4 per atom row
        int a4 = (ii & 31) * 4;
        float4 v = *(const float4*)(emb + (size_t)(n0 + atom) * 128 + a4);
        s_embT[(a4 + 0) * 16 + atom] = v.x;
        s_embT[(a4 + 1) * 16 + atom] = v.y;
        s_embT[(a4 + 2) * 16 + atom] = v.z;
        s_embT[(a4 + 3) * 16 + atom] = v.w;
    }
    #pragma unroll
    for (int i = 0; i < 4; i++) {
        int ii = tid + i * 256;
        int atom = ii >> 6, c = ii & 63;
        float v = acc[(size_t)(n0 + atom) * 64 + c];
        if (c < 16) s_gs[atom * 16 + c] = v;
        else        s_gv[atom * 48 + (c - 16)] = v;
    }
    if (tid < 16) s_q[tid] = qch[n0 + tid];
    __syncthreads();

    // ---- U[atom][gh] = sum_a emb[atom][a] * agh[a][gh] ----
    {
        const int gh4  = (tid & 127) * 4;   // 4 consecutive gh
        const int half = tid >> 7;          // atoms half*8 .. +7
        float u[32];
        #pragma unroll
        for (int i = 0; i < 32; i++) u[i] = 0.f;
        #pragma unroll 4
        for (int a = 0; a < 128; a++) {
            float4 w  = *(const float4*)(agh + a * 512 + gh4);
            float4 e0 = *(const float4*)(s_embT + a * 16 + half * 8);
            float4 e1 = *(const float4*)(s_embT + a * 16 + half * 8 + 4);
            float wv[4] = {w.x, w.y, w.z, w.w};
            float ev[8] = {e0.x, e0.y, e0.z, e0.w, e1.x, e1.y, e1.z, e1.w};
            #pragma unroll
            for (int j = 0; j < 4; j++)
                #pragma unroll
                for (int m = 0; m < 8; m++)
                    u[j * 8 + m] += wv[j] * ev[m];
        }
        #pragma unroll
        for (int m = 0; m < 8; m++) {
            int atom = half * 8 + m;
            float4 v = {u[0 * 8 + m], u[1 * 8 + m], u[2 * 8 + m], u[3 * 8 + m]};
            *(float4*)(s_U + atom * 512 + gh4) = v;
        }
    }
    __syncthreads();

    // ---- avf + safe_norm -> msg rows [128,160) ; zero rows [288,320) ----
    #pragma unroll
    for (int it = 0; it < 2; it++) {
        int i = tid + it * 256;
        int atom = i >> 5, h = i & 31;
        float v0 = 0.f, v1 = 0.f, v2 = 0.f;
        #pragma unroll
        for (int g = 0; g < 16; g++) {
            float uv = s_U[atom * 512 + g * 32 + h];
            v0 += uv * s_gv[atom * 48 + g];
            v1 += uv * s_gv[atom * 48 + 16 + g];
            v2 += uv * s_gv[atom * 48 + 32 + g];
        }
        float sq = v0 * v0 + v1 * v1 + v2 * v2;
        float nrm = (sq > 0.f) ? sqrtf(sq) : 0.f;
        s_msgT[(128 + h) * 16 + atom] = nrm;
        s_msgT[(288 + h) * 16 + atom] = 0.f;
    }

    // ---- mapped = GS_sum @ W_gf ; rad_emb rows [0,128) ; rad_q rows [160,288) ----
    {
        const int f = tid & 127;
        const int half = tid >> 7;
        float mp[8];
        #pragma unroll
        for (int a = 0; a < 8; a++) mp[a] = 0.f;
        #pragma unroll
        for (int g = 0; g < 16; g++) {
            float w = W_gf[g * 128 + f];
            #pragma unroll
            for (int a = 0; a < 8; a++)
                mp[a] += s_gs[(half * 8 + a) * 16 + g] * w;
        }
        #pragma unroll
        for (int a = 0; a < 8; a++) {
            int atom = half * 8 + a;
            float e = s_embT[f * 16 + atom];
            s_msgT[f * 16 + atom]         = e * mp[a];
            s_msgT[(160 + f) * 16 + atom] = s_q[atom] * mp[a];
        }
    }
    __syncthreads();

    // ---- MLP layer 1: h1 = gelu(msg @ W1 + b1), 320 -> 256 ----
    {
        const int o4 = (tid & 63) * 4;      // 4 consecutive output cols
        const int q4 = (tid >> 6) * 4;      // 4 consecutive atoms
        float acc1[16];
        #pragma unroll
        for (int i = 0; i < 16; i++) acc1[i] = 0.f;
        #pragma unroll 4
        for (int k = 0; k < 320; k++) {
            float4 w  = *(const float4*)(W1 + k * 256 + o4);
            float4 mm = *(const float4*)(s_msgT + k * 16 + q4);
            float wv[4] = {w.x, w.y, w.z, w.w};
            float mv[4] = {mm.x, mm.y, mm.z, mm.w};
            #pragma unroll
            for (int j = 0; j < 4; j++)
                #pragma unroll
                for (int m = 0; m < 4; m++)
                    acc1[j * 4 + m] += wv[j] * mv[m];
        }
        #pragma unroll
        for (int j = 0; j < 4; j++) {
            int o = o4 + j;
            float bb = b1[o];
            float4 v;
            v.x = gelu_exact(acc1[j * 4 + 0] + bb);
            v.y = gelu_exact(acc1[j * 4 + 1] + bb);
            v.z = gelu_exact(acc1[j * 4 + 2] + bb);
            v.w = gelu_exact(acc1[j * 4 + 3] + bb);
            *(float4*)(s_h1T + o * 16 + q4) = v;
        }
    }
    __syncthreads();

    // ---- MLP layer 2: h2 = gelu(h1 @ W2 + b2), 256 -> 128 ----
    {
        const int o4 = (tid & 31) * 4;
        const int a2 = (tid >> 5) * 2;
        float acc2[8];
        #pragma unroll
        for (int i = 0; i < 8; i++) acc2[i] = 0.f;
        #pragma unroll 4
        for (int k = 0; k < 256; k++) {
            float4 w  = *(const float4*)(W2 + k * 128 + o4);
            float2 hh = *(const float2*)(s_h1T + k * 16 + a2);
            float wv[4] = {w.x, w.y, w.z, w.w};
            float hv[2] = {hh.x, hh.y};
            #pragma unroll
            for (int j = 0; j < 4; j++)
                #pragma unroll
                for (int m = 0; m < 2; m++)
                    acc2[j * 2 + m] += wv[j] * hv[m];
        }
        #pragma unroll
        for (int j = 0; j < 4; j++) {
            int o = o4 + j;
            float bb = b2[o];
            float2 v;
            v.x = gelu_exact(acc2[j * 2 + 0] + bb);
            v.y = gelu_exact(acc2[j * 2 + 1] + bb);
            *(float2*)(s_h2T + o * 16 + a2) = v;
        }
    }
    __syncthreads();

    // ---- MLP layer 3: out = h2 @ W3 + b3, 128 -> 130 ----
    {
        const int o4 = (tid & 31) * 4 + 2;   // cols 2..129 (delta_a)
        const int a2 = (tid >> 5) * 2;
        float acc3[8];
        #pragma unroll
        for (int i = 0; i < 8; i++) acc3[i] = 0.f;
        #pragma unroll 4
        for (int k = 0; k < 128; k++) {
            const float* wp = W3 + k * 130 + o4;     // even element offset -> 8B aligned
            float2 wa = *(const float2*)(wp);
            float2 wb = *(const float2*)(wp + 2);
            float2 hh = *(const float2*)(s_h2T + k * 16 + a2);
            float wv[4] = {wa.x, wa.y, wb.x, wb.y};
            float hv[2] = {hh.x, hh.y};
            #pragma unroll
            for (int j = 0; j < 4; j++)
                #pragma unroll
                for (int m = 0; m < 2; m++)
                    acc3[j * 2 + m] += wv[j] * hv[m];
        }
        #pragma unroll
        for (int m = 0; m < 2; m++) {
            int n = n0 + a2 + m;
            float4 v;
            v.x = acc3[0 * 2 + m] + b3[o4 + 0];
            v.y = acc3[1 * 2 + m] + b3[o4 + 1];
            v.z = acc3[2 * 2 + m] + b3[o4 + 2];
            v.w = acc3[3 * 2 + m] + b3[o4 + 3];
            *(float4*)(out + (size_t)n * 128 + (o4 - 2)) = v;
        }

        // delta_q (col 0) and f (col 1)
        if (tid < 32) {
            int atom = tid >> 1, col = tid & 1;
            float s = 0.f;
            #pragma unroll 4
            for (int k = 0; k < 128; k++)
                s += s_h2T[k * 16 + atom] * W3[k * 130 + col];
            s += b3[col];
            out[(size_t)N_ATOMS * 128 + (size_t)col * N_ATOMS + (n0 + atom)] = s;
        }
    }
}

extern "C" void kernel_launch(void* const* d_in, const int* in_sizes, int n_in,
                              void* d_out, int out_size, void* d_ws, size_t ws_size,
                              hipStream_t stream)
{
    const float* emb  = (const float*)d_in[0];
    const float* qch  = (const float*)d_in[1];
    const int*   pidx = (const int*)d_in[2];
    const float* gs   = (const float*)d_in[3];
    const float* gv   = (const float*)d_in[4];
    const float* agh  = (const float*)d_in[5];
    const float* W_gf = (const float*)d_in[6];
    const float* W1   = (const float*)d_in[7];
    const float* b1   = (const float*)d_in[8];
    const float* W2   = (const float*)d_in[9];
    const float* b2   = (const float*)d_in[10];
    const float* W3   = (const float*)d_in[11];
    const float* b3   = (const float*)d_in[12];

    float* acc = (float*)d_ws;   // N*64 fp32 accumulators (12.8 MB)

    hipMemsetAsync(acc, 0, (size_t)N_ATOMS * 64 * sizeof(float), stream);

    scatter_kernel<<<(P_PAIRS * 64) / 256, 256, 0, stream>>>(
        pidx + P_PAIRS, gs, gv, acc);

    fused_atom_kernel<<<N_ATOMS / TA, 256, 0, stream>>>(
        emb, qch, acc, agh, W_gf, W1, b1, W2, b2, W3, b3, (float*)d_out);
}